// Round 6
// baseline (471.669 us; speedup 1.0000x reference)
//
#include <hip/hip_runtime.h>

// TripletLoss on MI355X — round 6: r2's 4096-block kernel + LDS transpose-reduce
// epilogue (replaces 128 shfl/thread), + last-block fused scalar reduce.
//
// Lesson from r3-r5: 512-block big-state designs (92/144/127 us) all lose to
// the 4096-block r2 structure (69 us, VGPR 64, ~5 blocks/CU co-resident):
// oversubscription is the latency-hiding mechanism here. This round changes
// ONE thing in the r2 kernel: the epilogue's DS-pipe cost.
//
//  - Gram via mfma_f32_16x16x32_bf16, 128x128 tile, A+B staged with
//    global_load_lds w16 + XOR swizzle (0 conflicts, verified r2).
//  - Mining in t-domain (t = nj - 2*dot), monotone in dist per row.
//  - Epilogue: per-lane partials -> LDS scratch [128][36] (16B-aligned rows,
//    <=2-way bank aliasing = free), 128 threads reduce rows via ds_read_b128.
//  - Cross-block merge: order-preserving uint atomicMax/Min.
//  - Final scalar: last-block ticket (threadfence + acq-rel + agent loads).

constexpr int N = 8192;
constexpr int D = 256;
constexpr float MARGIN = 0.3f;
constexpr float NEG_FALLBACK = 1e6f;
constexpr float TBIG = 1e30f;
constexpr int NBLK1 = 4096;  // 64 x 64 grid

typedef __attribute__((ext_vector_type(8))) __bf16 bf16x8;
typedef __attribute__((ext_vector_type(4))) float f32x4;

__device__ __forceinline__ unsigned enc_f(float f) {
  unsigned u = __float_as_uint(f);
  return (u >> 31) ? ~u : (u | 0x80000000u);
}
__device__ __forceinline__ float dec_f(unsigned e) {
  unsigned u = (e >> 31) ? (e ^ 0x80000000u) : ~e;
  return __uint_as_float(u);
}
__device__ __forceinline__ unsigned short f2bf_rtn(float x) {
  unsigned u = __float_as_uint(x);
  return (unsigned short)((u + 0x7fffu + ((u >> 16) & 1u)) >> 16);
}

// ---------------- pass 0: bf16 convert + norms + init ----------------

__global__ void tl_pass0f(const float* __restrict__ feat, float* __restrict__ norms,
                          unsigned* __restrict__ ap, unsigned* __restrict__ an,
                          unsigned short* __restrict__ P, float* __restrict__ out,
                          unsigned* __restrict__ done) {
  int row = blockIdx.x * 4 + (threadIdx.x >> 6);
  int lane = threadIdx.x & 63;
  float4 f = reinterpret_cast<const float4*>(feat + (size_t)row * D)[lane];
  ushort4 h;
  h.x = f2bf_rtn(f.x); h.y = f2bf_rtn(f.y); h.z = f2bf_rtn(f.z); h.w = f2bf_rtn(f.w);
  reinterpret_cast<ushort4*>(P + (size_t)row * D)[lane] = h;
  float s = fmaf(f.x, f.x, fmaf(f.y, f.y, fmaf(f.z, f.z, f.w * f.w)));
#pragma unroll
  for (int off = 32; off > 0; off >>= 1) s += __shfl_down(s, off, 64);
  if (lane == 0) {
    norms[row] = s;
    ap[row] = enc_f(-TBIG);
    an[row] = enc_f(TBIG);
  }
  if (row == 0 && lane == 0) { out[0] = 0.0f; *done = 0u; }
}

// ---------------- pass 1: fused Gram + hard mining + final reduce ----------------

__global__ __launch_bounds__(256, 3)
void tl_pass1m(const unsigned short* __restrict__ P, const int* __restrict__ labels,
               const float* __restrict__ norms,
               unsigned* __restrict__ ap, unsigned* __restrict__ an,
               unsigned* __restrict__ done, float* __restrict__ out) {
  __shared__ unsigned short lbuf[2][128][64];  // 32 KB: A/B panels, later scratch
  __shared__ float redf[4];
  __shared__ int lastFlag;

  unsigned short (*lA)[64] = lbuf[0];
  unsigned short (*lB)[64] = lbuf[1];

  const int tid = threadIdx.x;
  const int wave = tid >> 6;
  const int lane = tid & 63;
  const int c = lane & 15;
  const int q = lane >> 4;
  const int ib0 = blockIdx.y * 128;
  const int jb0 = blockIdx.x * 128;
  const int wi = (wave & 1) * 64;
  const int wj = (wave >> 1) * 64;

  f32x4 acc[4][4];
#pragma unroll
  for (int a = 0; a < 4; ++a)
#pragma unroll
    for (int b = 0; b < 4; ++b) acc[a][b] = (f32x4){0.f, 0.f, 0.f, 0.f};

  const int rsub = lane >> 3;
  const int gsw = (lane & 7) ^ (rsub & 7);

  for (int kc = 0; kc < D; kc += 64) {
#pragma unroll
    for (int t = 0; t < 4; ++t) {
      int rA = wave * 32 + t * 8;
      const unsigned short* gA = P + (size_t)(ib0 + rA + rsub) * D + kc + gsw * 8;
      __builtin_amdgcn_global_load_lds(
          (const __attribute__((address_space(1))) void*)gA,
          (__attribute__((address_space(3))) void*)&lA[rA][0], 16, 0, 0);
      const unsigned short* gB = P + (size_t)(jb0 + rA + rsub) * D + kc + gsw * 8;
      __builtin_amdgcn_global_load_lds(
          (const __attribute__((address_space(1))) void*)gB,
          (__attribute__((address_space(3))) void*)&lB[rA][0], 16, 0, 0);
    }
    __syncthreads();

#pragma unroll
    for (int ks = 0; ks < 2; ++ks) {
      bf16x8 af[4], bfr[4];
      const int gsel = ((ks * 4 + q) ^ (c & 7)) * 8;
#pragma unroll
      for (int a = 0; a < 4; ++a)
        af[a] = *(const bf16x8*)&lA[wi + a * 16 + c][gsel];
#pragma unroll
      for (int b = 0; b < 4; ++b)
        bfr[b] = *(const bf16x8*)&lB[wj + b * 16 + c][gsel];
#pragma unroll
      for (int a = 0; a < 4; ++a)
#pragma unroll
        for (int b = 0; b < 4; ++b)
          acc[a][b] = __builtin_amdgcn_mfma_f32_16x16x32_bf16(af[a], bfr[b], acc[a][b], 0, 0, 0);
    }
    __syncthreads();
  }

  // ---- mining: t = nj - 2*dot; per-lane partials over this lane's 4 cols ----
  int cj[4]; float nj[4]; int lj[4];
#pragma unroll
  for (int b = 0; b < 4; ++b) {
    cj[b] = jb0 + wj + b * 16 + c;
    nj[b] = norms[cj[b]];
    lj[b] = labels[cj[b]];
  }

  float tp[4][4], tn[4][4];
#pragma unroll
  for (int a = 0; a < 4; ++a) {
#pragma unroll
    for (int r = 0; r < 4; ++r) {
      int rg = ib0 + wi + a * 16 + q * 4 + r;  // C/D layout: row = quad*4 + reg
      int li = labels[rg];
      float vp = -TBIG, vn = TBIG;
#pragma unroll
      for (int b = 0; b < 4; ++b) {
        float t = fmaf(-2.f, acc[a][b][r], nj[b]);
        bool sm = (lj[b] == li);
        bool dg = (cj[b] == rg);
        vp = fmaxf(vp, (sm && !dg) ? t : -TBIG);
        vn = fminf(vn, sm ? TBIG : t);
      }
      tp[a][r] = vp;
      tn[a][r] = vn;
    }
  }

  // ---- transpose-reduce epilogue (replaces 128 shfl/thread) ----
  // S[128][36]: row stride 36 floats = 144 B (16B-aligned; <=2-way bank alias).
  // slot = (wave>>1)*16 + c : 32 partials per row (two col-half waves).
  float* S = (float*)lbuf;
  const int slot = (wave >> 1) * 16 + c;

#pragma unroll
  for (int a = 0; a < 4; ++a)
#pragma unroll
    for (int r = 0; r < 4; ++r)
      S[(wi + a * 16 + q * 4 + r) * 36 + slot] = tp[a][r];
  __syncthreads();
  float vp = 0.f;
  if (tid < 128) {
    const f32x4* Srow = (const f32x4*)&S[tid * 36];
    f32x4 m0 = Srow[0];
#pragma unroll
    for (int i = 1; i < 8; ++i) {
      f32x4 v = Srow[i];
      m0[0] = fmaxf(m0[0], v[0]); m0[1] = fmaxf(m0[1], v[1]);
      m0[2] = fmaxf(m0[2], v[2]); m0[3] = fmaxf(m0[3], v[3]);
    }
    vp = fmaxf(fmaxf(m0[0], m0[1]), fmaxf(m0[2], m0[3]));
  }
  __syncthreads();
#pragma unroll
  for (int a = 0; a < 4; ++a)
#pragma unroll
    for (int r = 0; r < 4; ++r)
      S[(wi + a * 16 + q * 4 + r) * 36 + slot] = tn[a][r];
  __syncthreads();
  if (tid < 128) {
    const f32x4* Srow = (const f32x4*)&S[tid * 36];
    f32x4 m0 = Srow[0];
#pragma unroll
    for (int i = 1; i < 8; ++i) {
      f32x4 v = Srow[i];
      m0[0] = fminf(m0[0], v[0]); m0[1] = fminf(m0[1], v[1]);
      m0[2] = fminf(m0[2], v[2]); m0[3] = fminf(m0[3], v[3]);
    }
    float vn = fminf(fminf(m0[0], m0[1]), fminf(m0[2], m0[3]));
    atomicMax(&ap[ib0 + tid], enc_f(vp));
    atomicMin(&an[ib0 + tid], enc_f(vn));
  }

  // ---- fused pass 2: last block computes the scalar loss (verified r4/r5) ----
  __threadfence();
  __syncthreads();
  if (tid == 0) {
    unsigned t = __hip_atomic_fetch_add(done, 1u, __ATOMIC_ACQ_REL, __HIP_MEMORY_SCOPE_AGENT);
    lastFlag = (t == NBLK1 - 1);
  }
  __syncthreads();
  if (lastFlag) {
    float sum = 0.f;
    for (int r = tid; r < N; r += 256) {
      unsigned pe = __hip_atomic_load(&ap[r], __ATOMIC_RELAXED, __HIP_MEMORY_SCOPE_AGENT);
      unsigned ne = __hip_atomic_load(&an[r], __ATOMIC_RELAXED, __HIP_MEMORY_SCOPE_AGENT);
      float ni = norms[r];
      float tpv = dec_f(pe), tnv = dec_f(ne);
      float dap = (tpv < -1e29f) ? 0.f : sqrtf(fmaxf(ni + tpv, 0.f));
      float dan = (tnv > 1e29f) ? NEG_FALLBACK : sqrtf(fmaxf(ni + tnv, 0.f));
      sum += fmaxf(0.f, MARGIN + dap - dan);
    }
#pragma unroll
    for (int off = 32; off > 0; off >>= 1) sum += __shfl_down(sum, off, 64);
    if (lane == 0) redf[wave] = sum;
    __syncthreads();
    if (tid == 0) out[0] = (redf[0] + redf[1] + redf[2] + redf[3]) * (1.0f / (float)N);
  }
}

// ---------------- fallback fp32 path (small ws) — round-1 known-good ----------------

constexpr int FB_BK = 32;
constexpr int FB_JSPLIT = 8;
constexpr int FB_JRANGE = N / FB_JSPLIT;
constexpr int FB_LDS = 132;

__global__ void tl_pass0_fb(const float* __restrict__ feat, float* __restrict__ norms,
                            float* __restrict__ ap, float* __restrict__ an,
                            float* __restrict__ out) {
  int row = blockIdx.x * 4 + (threadIdx.x >> 6);
  int lane = threadIdx.x & 63;
  float4 f = reinterpret_cast<const float4*>(feat + (size_t)row * D)[lane];
  float s = f.x * f.x + f.y * f.y + f.z * f.z + f.w * f.w;
#pragma unroll
  for (int off = 32; off > 0; off >>= 1) s += __shfl_down(s, off, 64);
  if (lane == 0) { norms[row] = s; ap[row] = 0.0f; an[row] = NEG_FALLBACK; }
  if (row == 0 && lane == 0) out[0] = 0.0f;
}

__global__ __launch_bounds__(256, 2)
void tl_pass1_fb(const float* __restrict__ feat, const int* __restrict__ labels,
                 const float* __restrict__ norms,
                 unsigned int* __restrict__ ap, unsigned int* __restrict__ an) {
  __shared__ float As[FB_BK][FB_LDS];
  __shared__ float Bs[FB_BK][FB_LDS];
  const int tid = threadIdx.x;
  const int tx = tid & 15, ty = tid >> 4;
  const int ib0 = blockIdx.y * 128;
  const int jbase = blockIdx.x * FB_JRANGE;
  float ni[8]; int li[8]; int ri[8];
#pragma unroll
  for (int a = 0; a < 8; ++a) {
    int r = ty * 4 + (a & 3) + ((a >> 2) << 6);
    ri[a] = ib0 + r; ni[a] = norms[ri[a]]; li[a] = labels[ri[a]];
  }
  float apv[8], anv[8];
#pragma unroll
  for (int a = 0; a < 8; ++a) { apv[a] = 0.0f; anv[a] = NEG_FALLBACK; }
  for (int jt = 0; jt < FB_JRANGE; jt += 128) {
    const int jb = jbase + jt;
    float acc[8][8];
#pragma unroll
    for (int a = 0; a < 8; ++a)
#pragma unroll
      for (int b = 0; b < 8; ++b) acc[a][b] = 0.0f;
    for (int kc = 0; kc < D; kc += FB_BK) {
#pragma unroll
      for (int u = 0; u < 4; ++u) {
        int lin = tid + u * 256;
        int row = lin >> 3, c4 = lin & 7;
        float4 va = *reinterpret_cast<const float4*>(feat + (size_t)(ib0 + row) * D + kc + c4 * 4);
        As[c4 * 4 + 0][row] = va.x; As[c4 * 4 + 1][row] = va.y;
        As[c4 * 4 + 2][row] = va.z; As[c4 * 4 + 3][row] = va.w;
        float4 vb = *reinterpret_cast<const float4*>(feat + (size_t)(jb + row) * D + kc + c4 * 4);
        Bs[c4 * 4 + 0][row] = vb.x; Bs[c4 * 4 + 1][row] = vb.y;
        Bs[c4 * 4 + 2][row] = vb.z; Bs[c4 * 4 + 3][row] = vb.w;
      }
      __syncthreads();
#pragma unroll 8
      for (int k = 0; k < FB_BK; ++k) {
        float4 a0 = *reinterpret_cast<const float4*>(&As[k][ty * 4]);
        float4 a1 = *reinterpret_cast<const float4*>(&As[k][64 + ty * 4]);
        float4 b0 = *reinterpret_cast<const float4*>(&Bs[k][tx * 4]);
        float4 b1 = *reinterpret_cast<const float4*>(&Bs[k][64 + tx * 4]);
        float av[8] = {a0.x, a0.y, a0.z, a0.w, a1.x, a1.y, a1.z, a1.w};
        float bv[8] = {b0.x, b0.y, b0.z, b0.w, b1.x, b1.y, b1.z, b1.w};
#pragma unroll
        for (int a = 0; a < 8; ++a)
#pragma unroll
          for (int b = 0; b < 8; ++b) acc[a][b] = fmaf(av[a], bv[b], acc[a][b]);
      }
      __syncthreads();
    }
#pragma unroll
    for (int b = 0; b < 8; ++b) {
      int cjx = jb + tx * 4 + (b & 3) + ((b >> 2) << 6);
      float njx = norms[cjx]; int ljx = labels[cjx];
#pragma unroll
      for (int a = 0; a < 8; ++a) {
        float sq = fmaxf(ni[a] + njx - 2.0f * acc[a][b], 0.0f);
        float dist = sqrtf(sq);
        if (li[a] == ljx) { if (ri[a] != cjx) apv[a] = fmaxf(apv[a], dist); }
        else anv[a] = fminf(anv[a], dist);
      }
    }
  }
  __syncthreads();
  float* red = &As[0][0];
#pragma unroll
  for (int a = 0; a < 8; ++a) {
    int r = ty * 4 + (a & 3) + ((a >> 2) << 6);
    red[r * 16 + tx] = apv[a];
  }
  __syncthreads();
  if (tid < 128) {
    float m = red[tid * 16];
#pragma unroll
    for (int t = 1; t < 16; ++t) m = fmaxf(m, red[tid * 16 + t]);
    atomicMax(&ap[ib0 + tid], __float_as_uint(m));
  }
  __syncthreads();
#pragma unroll
  for (int a = 0; a < 8; ++a) {
    int r = ty * 4 + (a & 3) + ((a >> 2) << 6);
    red[r * 16 + tx] = anv[a];
  }
  __syncthreads();
  if (tid < 128) {
    float m = red[tid * 16];
#pragma unroll
    for (int t = 1; t < 16; ++t) m = fminf(m, red[tid * 16 + t]);
    atomicMin(&an[ib0 + tid], __float_as_uint(m));
  }
}

__global__ void tl_pass2_fb(const float* __restrict__ ap, const float* __restrict__ an,
                            float* __restrict__ out) {
  int r = blockIdx.x * 256 + threadIdx.x;
  float v = fmaxf(0.0f, MARGIN + ap[r] - an[r]) * (1.0f / (float)N);
#pragma unroll
  for (int off = 32; off > 0; off >>= 1) v += __shfl_down(v, off, 64);
  __shared__ float red[4];
  int lane = threadIdx.x & 63, w = threadIdx.x >> 6;
  if (lane == 0) red[w] = v;
  __syncthreads();
  if (threadIdx.x == 0) atomicAdd(out, red[0] + red[1] + red[2] + red[3]);
}

// ---------------- launch ----------------

extern "C" void kernel_launch(void* const* d_in, const int* in_sizes, int n_in,
                              void* d_out, int out_size, void* d_ws, size_t ws_size,
                              hipStream_t stream) {
  const float* feat = (const float*)d_in[0];
  const int* labels = (const int*)d_in[1];
  float* out = (float*)d_out;

  // ws: norms[N] f32 | ap_enc[N] u32 | an_enc[N] u32 | done u32(+pad) | P[N*D] bf16
  float* norms = (float*)d_ws;
  unsigned* ap = (unsigned*)(norms + N);
  unsigned* an = ap + N;
  unsigned* done = an + N;
  unsigned short* P = (unsigned short*)(done + 4);  // keep P 16B-aligned
  const size_t NEED = 3 * (size_t)N * 4 + 16 + (size_t)N * D * 2;

  if (ws_size >= NEED) {
    tl_pass0f<<<N / 4, 256, 0, stream>>>(feat, norms, ap, an, P, out, done);
    dim3 grid1(N / 128, N / 128);  // 64 x 64 = 4096 blocks
    tl_pass1m<<<grid1, 256, 0, stream>>>(P, labels, norms, ap, an, done, out);
  } else {
    float* apf = (float*)ap;
    float* anf = (float*)an;
    tl_pass0_fb<<<N / 4, 256, 0, stream>>>(feat, norms, apf, anf, out);
    dim3 grid1(FB_JSPLIT, N / 128);
    tl_pass1_fb<<<grid1, 256, 0, stream>>>(feat, labels, norms, (unsigned*)apf, (unsigned*)anf);
    tl_pass2_fb<<<N / 256, 256, 0, stream>>>(apf, anf, out);
  }
}

// Round 7
// 110.449 us; speedup vs baseline: 4.2705x; 4.2705x over previous
//
#include <hip/hip_runtime.h>

// TripletLoss on MI355X — round 7: r2 kernel + transpose-reduce epilogue,
// NO device-scope fence/ticket (r6's 426-us regression traced to per-block
// __threadfence + acq-rel ticket: 4096 L2 writeback/invalidates evicted the
// streaming P panels on every XCD -> staging degraded to L3 latency).
//
//  - pass1m: r2's verified 128x128 MFMA structure (A+B via global_load_lds
//    w16 + XOR swizzle, 0 conflicts), mining in t-domain.
//  - Epilogue: LDS transpose-reduce (S[128][36], <=2-way bank alias) instead
//    of 128 shfl/thread; plain device-scope atomicMax/Min (no fence).
//  - pass2: separate small kernel (launch cost << L2-invalidation cost).

constexpr int N = 8192;
constexpr int D = 256;
constexpr float MARGIN = 0.3f;
constexpr float NEG_FALLBACK = 1e6f;
constexpr float TBIG = 1e30f;

typedef __attribute__((ext_vector_type(8))) __bf16 bf16x8;
typedef __attribute__((ext_vector_type(4))) float f32x4;

__device__ __forceinline__ unsigned enc_f(float f) {
  unsigned u = __float_as_uint(f);
  return (u >> 31) ? ~u : (u | 0x80000000u);
}
__device__ __forceinline__ float dec_f(unsigned e) {
  unsigned u = (e >> 31) ? (e ^ 0x80000000u) : ~e;
  return __uint_as_float(u);
}
__device__ __forceinline__ unsigned short f2bf_rtn(float x) {
  unsigned u = __float_as_uint(x);
  return (unsigned short)((u + 0x7fffu + ((u >> 16) & 1u)) >> 16);
}

// ---------------- pass 0: bf16 convert + norms + init ----------------

__global__ void tl_pass0f(const float* __restrict__ feat, float* __restrict__ norms,
                          unsigned* __restrict__ ap, unsigned* __restrict__ an,
                          unsigned short* __restrict__ P, float* __restrict__ out) {
  int row = blockIdx.x * 4 + (threadIdx.x >> 6);
  int lane = threadIdx.x & 63;
  float4 f = reinterpret_cast<const float4*>(feat + (size_t)row * D)[lane];
  ushort4 h;
  h.x = f2bf_rtn(f.x); h.y = f2bf_rtn(f.y); h.z = f2bf_rtn(f.z); h.w = f2bf_rtn(f.w);
  reinterpret_cast<ushort4*>(P + (size_t)row * D)[lane] = h;
  float s = fmaf(f.x, f.x, fmaf(f.y, f.y, fmaf(f.z, f.z, f.w * f.w)));
#pragma unroll
  for (int off = 32; off > 0; off >>= 1) s += __shfl_down(s, off, 64);
  if (lane == 0) {
    norms[row] = s;
    ap[row] = enc_f(-TBIG);
    an[row] = enc_f(TBIG);
  }
  if (row == 0 && lane == 0) out[0] = 0.0f;
}

// ---------------- pass 1: fused Gram + hard mining ----------------

__global__ __launch_bounds__(256, 3)
void tl_pass1m(const unsigned short* __restrict__ P, const int* __restrict__ labels,
               const float* __restrict__ norms,
               unsigned* __restrict__ ap, unsigned* __restrict__ an) {
  __shared__ unsigned short lbuf[2][128][64];  // 32 KB: A/B panels, later scratch

  unsigned short (*lA)[64] = lbuf[0];
  unsigned short (*lB)[64] = lbuf[1];

  const int tid = threadIdx.x;
  const int wave = tid >> 6;
  const int lane = tid & 63;
  const int c = lane & 15;
  const int q = lane >> 4;
  const int ib0 = blockIdx.y * 128;
  const int jb0 = blockIdx.x * 128;
  const int wi = (wave & 1) * 64;
  const int wj = (wave >> 1) * 64;

  f32x4 acc[4][4];
#pragma unroll
  for (int a = 0; a < 4; ++a)
#pragma unroll
    for (int b = 0; b < 4; ++b) acc[a][b] = (f32x4){0.f, 0.f, 0.f, 0.f};

  const int rsub = lane >> 3;
  const int gsw = (lane & 7) ^ (rsub & 7);

  for (int kc = 0; kc < D; kc += 64) {
#pragma unroll
    for (int t = 0; t < 4; ++t) {
      int rA = wave * 32 + t * 8;
      const unsigned short* gA = P + (size_t)(ib0 + rA + rsub) * D + kc + gsw * 8;
      __builtin_amdgcn_global_load_lds(
          (const __attribute__((address_space(1))) void*)gA,
          (__attribute__((address_space(3))) void*)&lA[rA][0], 16, 0, 0);
      const unsigned short* gB = P + (size_t)(jb0 + rA + rsub) * D + kc + gsw * 8;
      __builtin_amdgcn_global_load_lds(
          (const __attribute__((address_space(1))) void*)gB,
          (__attribute__((address_space(3))) void*)&lB[rA][0], 16, 0, 0);
    }
    __syncthreads();

#pragma unroll
    for (int ks = 0; ks < 2; ++ks) {
      bf16x8 af[4], bfr[4];
      const int gsel = ((ks * 4 + q) ^ (c & 7)) * 8;
#pragma unroll
      for (int a = 0; a < 4; ++a)
        af[a] = *(const bf16x8*)&lA[wi + a * 16 + c][gsel];
#pragma unroll
      for (int b = 0; b < 4; ++b)
        bfr[b] = *(const bf16x8*)&lB[wj + b * 16 + c][gsel];
#pragma unroll
      for (int a = 0; a < 4; ++a)
#pragma unroll
        for (int b = 0; b < 4; ++b)
          acc[a][b] = __builtin_amdgcn_mfma_f32_16x16x32_bf16(af[a], bfr[b], acc[a][b], 0, 0, 0);
    }
    __syncthreads();
  }

  // ---- mining: t = nj - 2*dot; per-lane partials over this lane's 4 cols ----
  int cj[4]; float nj[4]; int lj[4];
#pragma unroll
  for (int b = 0; b < 4; ++b) {
    cj[b] = jb0 + wj + b * 16 + c;
    nj[b] = norms[cj[b]];
    lj[b] = labels[cj[b]];
  }

  float tp[4][4], tn[4][4];
#pragma unroll
  for (int a = 0; a < 4; ++a) {
#pragma unroll
    for (int r = 0; r < 4; ++r) {
      int rg = ib0 + wi + a * 16 + q * 4 + r;  // C/D layout: row = quad*4 + reg
      int li = labels[rg];
      float vp = -TBIG, vn = TBIG;
#pragma unroll
      for (int b = 0; b < 4; ++b) {
        float t = fmaf(-2.f, acc[a][b][r], nj[b]);
        bool sm = (lj[b] == li);
        bool dg = (cj[b] == rg);
        vp = fmaxf(vp, (sm && !dg) ? t : -TBIG);
        vn = fminf(vn, sm ? TBIG : t);
      }
      tp[a][r] = vp;
      tn[a][r] = vn;
    }
  }

  // ---- transpose-reduce epilogue: S[128][36], 32 partials per row ----
  float* S = (float*)lbuf;
  const int slot = (wave >> 1) * 16 + c;

#pragma unroll
  for (int a = 0; a < 4; ++a)
#pragma unroll
    for (int r = 0; r < 4; ++r)
      S[(wi + a * 16 + q * 4 + r) * 36 + slot] = tp[a][r];
  __syncthreads();
  float vp = 0.f;
  if (tid < 128) {
    const f32x4* Srow = (const f32x4*)&S[tid * 36];
    f32x4 m0 = Srow[0];
#pragma unroll
    for (int i = 1; i < 8; ++i) {
      f32x4 v = Srow[i];
      m0[0] = fmaxf(m0[0], v[0]); m0[1] = fmaxf(m0[1], v[1]);
      m0[2] = fmaxf(m0[2], v[2]); m0[3] = fmaxf(m0[3], v[3]);
    }
    vp = fmaxf(fmaxf(m0[0], m0[1]), fmaxf(m0[2], m0[3]));
  }
  __syncthreads();
#pragma unroll
  for (int a = 0; a < 4; ++a)
#pragma unroll
    for (int r = 0; r < 4; ++r)
      S[(wi + a * 16 + q * 4 + r) * 36 + slot] = tn[a][r];
  __syncthreads();
  if (tid < 128) {
    const f32x4* Srow = (const f32x4*)&S[tid * 36];
    f32x4 m0 = Srow[0];
#pragma unroll
    for (int i = 1; i < 8; ++i) {
      f32x4 v = Srow[i];
      m0[0] = fminf(m0[0], v[0]); m0[1] = fminf(m0[1], v[1]);
      m0[2] = fminf(m0[2], v[2]); m0[3] = fminf(m0[3], v[3]);
    }
    float vn = fminf(fminf(m0[0], m0[1]), fminf(m0[2], m0[3]));
    atomicMax(&ap[ib0 + tid], enc_f(vp));   // plain device RMW: no cache inval
    atomicMin(&an[ib0 + tid], enc_f(vn));
  }
}

// ---------------- pass 2: per-row loss -> mean ----------------

__global__ void tl_pass2f(const unsigned* __restrict__ ap, const unsigned* __restrict__ an,
                          const float* __restrict__ norms, float* __restrict__ out) {
  int r = blockIdx.x * 256 + threadIdx.x;
  float ni = norms[r];
  float tpv = dec_f(ap[r]);
  float tnv = dec_f(an[r]);
  float dap = (tpv < -1e29f) ? 0.f : sqrtf(fmaxf(ni + tpv, 0.f));
  float dan = (tnv > 1e29f) ? NEG_FALLBACK : sqrtf(fmaxf(ni + tnv, 0.f));
  float v = fmaxf(0.f, MARGIN + dap - dan) * (1.0f / (float)N);
#pragma unroll
  for (int off = 32; off > 0; off >>= 1) v += __shfl_down(v, off, 64);
  __shared__ float red[4];
  int lane = threadIdx.x & 63, w = threadIdx.x >> 6;
  if (lane == 0) red[w] = v;
  __syncthreads();
  if (threadIdx.x == 0) atomicAdd(out, red[0] + red[1] + red[2] + red[3]);
}

// ---------------- fallback fp32 path (small ws) — round-1 known-good ----------------

constexpr int FB_BK = 32;
constexpr int FB_JSPLIT = 8;
constexpr int FB_JRANGE = N / FB_JSPLIT;
constexpr int FB_LDS = 132;

__global__ void tl_pass0_fb(const float* __restrict__ feat, float* __restrict__ norms,
                            float* __restrict__ ap, float* __restrict__ an,
                            float* __restrict__ out) {
  int row = blockIdx.x * 4 + (threadIdx.x >> 6);
  int lane = threadIdx.x & 63;
  float4 f = reinterpret_cast<const float4*>(feat + (size_t)row * D)[lane];
  float s = f.x * f.x + f.y * f.y + f.z * f.z + f.w * f.w;
#pragma unroll
  for (int off = 32; off > 0; off >>= 1) s += __shfl_down(s, off, 64);
  if (lane == 0) { norms[row] = s; ap[row] = 0.0f; an[row] = NEG_FALLBACK; }
  if (row == 0 && lane == 0) out[0] = 0.0f;
}

__global__ __launch_bounds__(256, 2)
void tl_pass1_fb(const float* __restrict__ feat, const int* __restrict__ labels,
                 const float* __restrict__ norms,
                 unsigned int* __restrict__ ap, unsigned int* __restrict__ an) {
  __shared__ float As[FB_BK][FB_LDS];
  __shared__ float Bs[FB_BK][FB_LDS];
  const int tid = threadIdx.x;
  const int tx = tid & 15, ty = tid >> 4;
  const int ib0 = blockIdx.y * 128;
  const int jbase = blockIdx.x * FB_JRANGE;
  float ni[8]; int li[8]; int ri[8];
#pragma unroll
  for (int a = 0; a < 8; ++a) {
    int r = ty * 4 + (a & 3) + ((a >> 2) << 6);
    ri[a] = ib0 + r; ni[a] = norms[ri[a]]; li[a] = labels[ri[a]];
  }
  float apv[8], anv[8];
#pragma unroll
  for (int a = 0; a < 8; ++a) { apv[a] = 0.0f; anv[a] = NEG_FALLBACK; }
  for (int jt = 0; jt < FB_JRANGE; jt += 128) {
    const int jb = jbase + jt;
    float acc[8][8];
#pragma unroll
    for (int a = 0; a < 8; ++a)
#pragma unroll
      for (int b = 0; b < 8; ++b) acc[a][b] = 0.0f;
    for (int kc = 0; kc < D; kc += FB_BK) {
#pragma unroll
      for (int u = 0; u < 4; ++u) {
        int lin = tid + u * 256;
        int row = lin >> 3, c4 = lin & 7;
        float4 va = *reinterpret_cast<const float4*>(feat + (size_t)(ib0 + row) * D + kc + c4 * 4);
        As[c4 * 4 + 0][row] = va.x; As[c4 * 4 + 1][row] = va.y;
        As[c4 * 4 + 2][row] = va.z; As[c4 * 4 + 3][row] = va.w;
        float4 vb = *reinterpret_cast<const float4*>(feat + (size_t)(jb + row) * D + kc + c4 * 4);
        Bs[c4 * 4 + 0][row] = vb.x; Bs[c4 * 4 + 1][row] = vb.y;
        Bs[c4 * 4 + 2][row] = vb.z; Bs[c4 * 4 + 3][row] = vb.w;
      }
      __syncthreads();
#pragma unroll 8
      for (int k = 0; k < FB_BK; ++k) {
        float4 a0 = *reinterpret_cast<const float4*>(&As[k][ty * 4]);
        float4 a1 = *reinterpret_cast<const float4*>(&As[k][64 + ty * 4]);
        float4 b0 = *reinterpret_cast<const float4*>(&Bs[k][tx * 4]);
        float4 b1 = *reinterpret_cast<const float4*>(&Bs[k][64 + tx * 4]);
        float av[8] = {a0.x, a0.y, a0.z, a0.w, a1.x, a1.y, a1.z, a1.w};
        float bv[8] = {b0.x, b0.y, b0.z, b0.w, b1.x, b1.y, b1.z, b1.w};
#pragma unroll
        for (int a = 0; a < 8; ++a)
#pragma unroll
          for (int b = 0; b < 8; ++b) acc[a][b] = fmaf(av[a], bv[b], acc[a][b]);
      }
      __syncthreads();
    }
#pragma unroll
    for (int b = 0; b < 8; ++b) {
      int cjx = jb + tx * 4 + (b & 3) + ((b >> 2) << 6);
      float njx = norms[cjx]; int ljx = labels[cjx];
#pragma unroll
      for (int a = 0; a < 8; ++a) {
        float sq = fmaxf(ni[a] + njx - 2.0f * acc[a][b], 0.0f);
        float dist = sqrtf(sq);
        if (li[a] == ljx) { if (ri[a] != cjx) apv[a] = fmaxf(apv[a], dist); }
        else anv[a] = fminf(anv[a], dist);
      }
    }
  }
  __syncthreads();
  float* red = &As[0][0];
#pragma unroll
  for (int a = 0; a < 8; ++a) {
    int r = ty * 4 + (a & 3) + ((a >> 2) << 6);
    red[r * 16 + tx] = apv[a];
  }
  __syncthreads();
  if (tid < 128) {
    float m = red[tid * 16];
#pragma unroll
    for (int t = 1; t < 16; ++t) m = fmaxf(m, red[tid * 16 + t]);
    atomicMax(&ap[ib0 + tid], __float_as_uint(m));
  }
  __syncthreads();
#pragma unroll
  for (int a = 0; a < 8; ++a) {
    int r = ty * 4 + (a & 3) + ((a >> 2) << 6);
    red[r * 16 + tx] = anv[a];
  }
  __syncthreads();
  if (tid < 128) {
    float m = red[tid * 16];
#pragma unroll
    for (int t = 1; t < 16; ++t) m = fminf(m, red[tid * 16 + t]);
    atomicMin(&an[ib0 + tid], __float_as_uint(m));
  }
}

__global__ void tl_pass2_fb(const float* __restrict__ ap, const float* __restrict__ an,
                            float* __restrict__ out) {
  int r = blockIdx.x * 256 + threadIdx.x;
  float v = fmaxf(0.0f, MARGIN + ap[r] - an[r]) * (1.0f / (float)N);
#pragma unroll
  for (int off = 32; off > 0; off >>= 1) v += __shfl_down(v, off, 64);
  __shared__ float red[4];
  int lane = threadIdx.x & 63, w = threadIdx.x >> 6;
  if (lane == 0) red[w] = v;
  __syncthreads();
  if (threadIdx.x == 0) atomicAdd(out, red[0] + red[1] + red[2] + red[3]);
}

// ---------------- launch ----------------

extern "C" void kernel_launch(void* const* d_in, const int* in_sizes, int n_in,
                              void* d_out, int out_size, void* d_ws, size_t ws_size,
                              hipStream_t stream) {
  const float* feat = (const float*)d_in[0];
  const int* labels = (const int*)d_in[1];
  float* out = (float*)d_out;

  // ws: norms[N] f32 | ap_enc[N] u32 | an_enc[N] u32 | pad | P[N*D] bf16
  float* norms = (float*)d_ws;
  unsigned* ap = (unsigned*)(norms + N);
  unsigned* an = ap + N;
  unsigned short* P = (unsigned short*)(an + N + 4);  // 16B-aligned
  const size_t NEED = 3 * (size_t)N * 4 + 16 + (size_t)N * D * 2;

  if (ws_size >= NEED) {
    tl_pass0f<<<N / 4, 256, 0, stream>>>(feat, norms, ap, an, P, out);
    dim3 grid1(N / 128, N / 128);  // 64 x 64 = 4096 blocks
    tl_pass1m<<<grid1, 256, 0, stream>>>(P, labels, norms, ap, an);
    tl_pass2f<<<N / 256, 256, 0, stream>>>(ap, an, norms, out);
  } else {
    float* apf = (float*)ap;
    float* anf = (float*)an;
    tl_pass0_fb<<<N / 4, 256, 0, stream>>>(feat, norms, apf, anf, out);
    dim3 grid1(FB_JSPLIT, N / 128);
    tl_pass1_fb<<<grid1, 256, 0, stream>>>(feat, labels, norms, (unsigned*)apf, (unsigned*)anf);
    tl_pass2_fb<<<N / 256, 256, 0, stream>>>(apf, anf, out);
  }
}